// Round 5
// baseline (165.770 us; speedup 1.0000x reference)
//
#include <hip/hip_runtime.h>

#define MAX_POINTS 32
#define C_OUT 64
#define EPS 1e-5f

// ws layout (floats):
//  [0 .. NSET*16)       : NSET accumulator sets, 16 floats each (64 B apart)
//     set s, moment i -> ws[s*16 + i]
//     i in [0..3]  : sum x ; i in [4..13] : xx,xy,xz,xw,yy,yz,yw,zz,zw,ww ; i==14 : count
//  [CNT_IDX]            : int done-counter
//  [FIN_IDX .. +15)     : finalized moments (written by last stats block)
#define NMOM 15
#define NSET 32
#define CNT_IDX (NSET * 16)
#define FIN_IDX (NSET * 16 + 16)
#define WS_FLOATS (NSET * 16 + 32)

#define STATS_BLOCKS 1024

// ---------------- Pass 1: moment reduction + last-block finalize ------------
__global__ __launch_bounds__(256) void vfe_stats(
    const float* __restrict__ x, const int* __restrict__ vnp,
    float* __restrict__ ws, int M)
{
    const int tid    = blockIdx.x * 256 + threadIdx.x;
    const int stride = gridDim.x * 256;
    const int total  = M * MAX_POINTS;            // flat float4 slots

    float a[NMOM];
    #pragma unroll
    for (int i = 0; i < NMOM; ++i) a[i] = 0.f;

    const float4* __restrict__ xq = (const float4*)x;
    for (int i = tid; i < total; i += stride) {
        const float4 q0 = xq[i];                  // unconditional coalesced load
        const int   n   = vnp[i >> 5];            // independent, overlaps q0
        const float mk  = ((i & 31) < n) ? 1.f : 0.f;
        const float qx = q0.x * mk, qy = q0.y * mk, qz = q0.z * mk, qw = q0.w * mk;
        a[0] += qx; a[1] += qy; a[2] += qz; a[3] += qw;
        a[4]  = fmaf(qx, qx, a[4]);
        a[5]  = fmaf(qx, qy, a[5]);
        a[6]  = fmaf(qx, qz, a[6]);
        a[7]  = fmaf(qx, qw, a[7]);
        a[8]  = fmaf(qy, qy, a[8]);
        a[9]  = fmaf(qy, qz, a[9]);
        a[10] = fmaf(qy, qw, a[10]);
        a[11] = fmaf(qz, qz, a[11]);
        a[12] = fmaf(qz, qw, a[12]);
        a[13] = fmaf(qw, qw, a[13]);
        a[14] += mk;
    }

    // wave reduce (64 lanes)
    #pragma unroll
    for (int i = 0; i < NMOM; ++i) {
        float v = a[i];
        #pragma unroll
        for (int off = 32; off > 0; off >>= 1)
            v += __shfl_down(v, off, 64);
        a[i] = v;
    }

    // block reduce: 4 waves -> LDS -> 15 atomics into this block's set
    __shared__ float bl[4][NMOM];
    __shared__ int   is_last;
    const int lane = threadIdx.x & 63;
    const int wid  = threadIdx.x >> 6;
    if (lane == 0) {
        #pragma unroll
        for (int i = 0; i < NMOM; ++i) bl[wid][i] = a[i];
    }
    __syncthreads();
    const int set = blockIdx.x & (NSET - 1);      // spread over 32 L2 lines
    if (threadIdx.x < NMOM) {
        const int i = threadIdx.x;
        atomicAdd(&ws[set * 16 + i], bl[0][i] + bl[1][i] + bl[2][i] + bl[3][i]);
    }
    __threadfence();                              // my atomics before my counter tick
    __syncthreads();
    if (threadIdx.x == 0) {
        const int old = atomicAdd((int*)&ws[CNT_IDX], 1);
        is_last = (old == gridDim.x - 1);
    }
    __syncthreads();

    if (is_last && threadIdx.x < 64) {
        // lanes 0..31 each own one set; atomic-read (device-coherent) the 15 moments
        const int s = threadIdx.x;
        float v[NMOM];
        #pragma unroll
        for (int i = 0; i < NMOM; ++i)
            v[i] = (s < NSET) ? atomicAdd(&ws[s * 16 + i], 0.0f) : 0.f;
        #pragma unroll
        for (int i = 0; i < NMOM; ++i) {
            float t = v[i];
            #pragma unroll
            for (int off = 32; off > 0; off >>= 1)
                t += __shfl_down(t, off, 64);
            v[i] = t;
        }
        if (threadIdx.x == 0) {
            #pragma unroll
            for (int i = 0; i < NMOM; ++i) ws[FIN_IDX + i] = v[i];
        }
    }
}

// ---------------- Pass 2: fixed-unroll branchless bodies --------------------
// Wave = 4 voxels, lane = channel. BN affine folded into weights: per point
// v = relu(dot(q, wA) + c0), 6 VALU. Fixed trip count NP -> all broadcast
// loads issue back-to-back, one wait per body.
template<int NP>
__device__ __forceinline__ float voxel_body(
    const float4* __restrict__ xq, int n, float4 wA, float c0)
{
    float acc0 = 0.f, acc1 = 0.f, acc2 = 0.f, acc3 = 0.f;
    #pragma unroll
    for (int p = 0; p < NP; ++p) {
        const float4 q = xq[p];
        float v = fmaf(q.x, wA.x, fmaf(q.y, wA.y,
                  fmaf(q.z, wA.z, fmaf(q.w, wA.w, c0))));
        v = fmaxf(v, 0.f);
        if (p >= NP - 8) v = (p < n) ? v : 0.f;   // only last 8 need the mask
        if      ((p & 3) == 0) acc0 += v;
        else if ((p & 3) == 1) acc1 += v;
        else if ((p & 3) == 2) acc2 += v;
        else                   acc3 += v;
    }
    return (acc0 + acc1) + (acc2 + acc3);
}

__global__ __launch_bounds__(256) void vfe_out(
    const float* __restrict__ x, const int* __restrict__ vnp,
    const float* __restrict__ W, const float* __restrict__ b,
    const float* __restrict__ gamma, const float* __restrict__ beta,
    const float* __restrict__ ws, float* __restrict__ out, int M)
{
    const int lane = threadIdx.x & 63;            // channel
    const int wid  = threadIdx.x >> 6;
    const int gw   = blockIdx.x * 4 + wid;        // global wave id

    // finalized moments: 4 uniform float4 loads
    const float4* __restrict__ wsf = (const float4*)(ws + FIN_IDX);
    const float4 f0 = wsf[0], f1 = wsf[1], f2 = wsf[2], f3 = wsf[3];
    const float mom[NMOM] = { f0.x, f0.y, f0.z, f0.w,
                              f1.x, f1.y, f1.z, f1.w,
                              f2.x, f2.y, f2.z, f2.w,
                              f3.x, f3.y, f3.z };

    // Per-lane BN affine from the 15 moments
    const float4 w4  = ((const float4*)W)[lane];
    const float bias = b[lane];
    const float cnt  = mom[14];
    const float nv   = fmaxf(cnt, 1.0f);
    const float wdots = w4.x*mom[0] + w4.y*mom[1] + w4.z*mom[2] + w4.w*mom[3];
    const float mu   = (wdots + cnt * bias) / nv;
    const float q2 = mom[4]*w4.x*w4.x + mom[8]*w4.y*w4.y + mom[11]*w4.z*w4.z + mom[13]*w4.w*w4.w
                   + 2.f*(mom[5]*w4.x*w4.y + mom[6]*w4.x*w4.z + mom[7]*w4.x*w4.w
                        + mom[9]*w4.y*w4.z + mom[10]*w4.y*w4.w + mom[12]*w4.z*w4.w);
    const float SS  = q2 + 2.f*bias*wdots + cnt*bias*bias;   // sum h^2 over valid
    const float var = fmaxf(SS / nv - mu * mu, 0.f);
    const float A   = gamma[lane] * rsqrtf(var + EPS);
    const float B   = fmaf(-mu, A, beta[lane]);
    // fold: relu(h*A+B) = relu(dot(q, w*A) + (b*A+B))
    const float4 wA = make_float4(w4.x * A, w4.y * A, w4.z * A, w4.w * A);
    const float  c0 = fmaf(bias, A, B);

    const int m_base = gw * 4;
    if (m_base >= M) return;

    int4 n4;
    if (m_base + 3 < M) {
        n4 = *(const int4*)(vnp + m_base);        // one 16B wave-uniform load
    } else {
        n4.x = vnp[m_base];
        n4.y = (m_base + 1 < M) ? vnp[m_base + 1] : 0;
        n4.z = (m_base + 2 < M) ? vnp[m_base + 2] : 0;
        n4.w = (m_base + 3 < M) ? vnp[m_base + 3] : 0;
    }
    const int ns[4] = { n4.x, n4.y, n4.z, n4.w };

    #pragma unroll
    for (int v = 0; v < 4; ++v) {
        const int m = m_base + v;
        if (m >= M) break;                        // uniform branch
        const int n = ns[v];
        const float4* __restrict__ xq = (const float4*)x + (size_t)m * MAX_POINTS;
        float acc;
        if      (n > 24) acc = voxel_body<32>(xq, n, wA, c0);
        else if (n > 16) acc = voxel_body<24>(xq, n, wA, c0);
        else if (n >  8) acc = voxel_body<16>(xq, n, wA, c0);
        else if (n >  0) acc = voxel_body< 8>(xq, n, wA, c0);
        else             acc = 0.f;
        const float rn = 1.0f / fmaxf((float)n, 1.0f);
        out[(size_t)m * C_OUT + lane] = acc * rn; // coalesced 256 B/wave store
    }
}

extern "C" void kernel_launch(void* const* d_in, const int* in_sizes, int n_in,
                              void* d_out, int out_size, void* d_ws, size_t ws_size,
                              hipStream_t stream) {
    const float* x     = (const float*)d_in[0];
    const int*   vnp   = (const int*)  d_in[1];
    const float* W     = (const float*)d_in[2];
    const float* b     = (const float*)d_in[3];
    const float* gamma = (const float*)d_in[4];
    const float* beta  = (const float*)d_in[5];
    float* out = (float*)d_out;
    float* ws  = (float*)d_ws;
    const int M = in_sizes[1];                    // 40000 voxels

    hipMemsetAsync(d_ws, 0, WS_FLOATS * sizeof(float), stream);
    vfe_stats<<<STATS_BLOCKS, 256, 0, stream>>>(x, vnp, ws, M);
    const int nwaves = (M + 3) / 4;               // 4 voxels per wave
    const int nblk   = (nwaves + 3) / 4;          // 4 waves per block
    vfe_out<<<nblk, 256, 0, stream>>>(x, vnp, W, b, gamma, beta, ws, out, M);
}

// Round 6
// 115.522 us; speedup vs baseline: 1.4350x; 1.4350x over previous
//
#include <hip/hip_runtime.h>

#define MAX_POINTS 32
#define C_OUT 64
#define EPS 1e-5f

// ws layout (floats): NSET accumulator sets, 16 floats each (64 B apart).
// set s, moment i -> ws[s*16 + i]
//  i in [0..3]  : sum x   (sx, sy, sz, sw)
//  i in [4..13] : second moments xx,xy,xz,xw,yy,yz,yw,zz,zw,ww
//  i == 14      : valid-point count
// No fence / no finalize: vfe_out sums the sets per wave (cheap, uniform).
#define NMOM 15
#define NSET 16
#define WS_FLOATS (NSET * 16)
#define STATS_BLOCKS 512

// ---------------- Pass 1: 15-scalar moment reduction (streaming) ------------
__global__ __launch_bounds__(256) void vfe_stats(
    const float* __restrict__ x, const int* __restrict__ vnp,
    float* __restrict__ ws, int M)
{
    const int tid    = blockIdx.x * 256 + threadIdx.x;
    const int stride = gridDim.x * 256;
    const int total  = M * MAX_POINTS;            // flat float4 slots

    float a[NMOM];
    #pragma unroll
    for (int i = 0; i < NMOM; ++i) a[i] = 0.f;

    const float4* __restrict__ xq = (const float4*)x;
    for (int i = tid; i < total; i += stride) {
        const float4 q0 = xq[i];                  // unconditional coalesced load
        const int   n   = vnp[i >> 5];            // independent, overlaps q0
        const float mk  = ((i & 31) < n) ? 1.f : 0.f;
        const float qx = q0.x * mk, qy = q0.y * mk, qz = q0.z * mk, qw = q0.w * mk;
        a[0] += qx; a[1] += qy; a[2] += qz; a[3] += qw;
        a[4]  = fmaf(qx, qx, a[4]);
        a[5]  = fmaf(qx, qy, a[5]);
        a[6]  = fmaf(qx, qz, a[6]);
        a[7]  = fmaf(qx, qw, a[7]);
        a[8]  = fmaf(qy, qy, a[8]);
        a[9]  = fmaf(qy, qz, a[9]);
        a[10] = fmaf(qy, qw, a[10]);
        a[11] = fmaf(qz, qz, a[11]);
        a[12] = fmaf(qz, qw, a[12]);
        a[13] = fmaf(qw, qw, a[13]);
        a[14] += mk;
    }

    // wave reduce (64 lanes)
    #pragma unroll
    for (int i = 0; i < NMOM; ++i) {
        float v = a[i];
        #pragma unroll
        for (int off = 32; off > 0; off >>= 1)
            v += __shfl_down(v, off, 64);
        a[i] = v;
    }

    // block reduce: 4 waves -> LDS -> 15 atomics into this block's set.
    // NO __threadfence / done-counter here: R5 measured the per-block
    // device-scope fence tail at ~60 us. Plain device-scope atomics are
    // already coherent for the next kernel launch.
    __shared__ float bl[4][NMOM];
    const int lane = threadIdx.x & 63;
    const int wid  = threadIdx.x >> 6;
    if (lane == 0) {
        #pragma unroll
        for (int i = 0; i < NMOM; ++i) bl[wid][i] = a[i];
    }
    __syncthreads();
    if (threadIdx.x < NMOM) {
        const int i = threadIdx.x;
        const int set = blockIdx.x & (NSET - 1);  // spread over 16 L2 lines
        atomicAdd(&ws[set * 16 + i], bl[0][i] + bl[1][i] + bl[2][i] + bl[3][i]);
    }
}

// ---------------- Pass 2: fixed-unroll branchless bodies --------------------
// Wave = 4 voxels, lane = channel. BN affine folded into weights: per point
// v = relu(dot(q, wA) + c0) -> 6 VALU. Fixed trip count NP lets all broadcast
// loads issue back-to-back, one wait per body.
template<int NP>
__device__ __forceinline__ float voxel_body(
    const float4* __restrict__ xq, int n, float4 wA, float c0)
{
    float acc0 = 0.f, acc1 = 0.f, acc2 = 0.f, acc3 = 0.f;
    #pragma unroll
    for (int p = 0; p < NP; ++p) {
        const float4 q = xq[p];
        float v = fmaf(q.x, wA.x, fmaf(q.y, wA.y,
                  fmaf(q.z, wA.z, fmaf(q.w, wA.w, c0))));
        v = fmaxf(v, 0.f);
        if (p >= NP - 8) v = (p < n) ? v : 0.f;   // only last 8 need the mask
        if      ((p & 3) == 0) acc0 += v;
        else if ((p & 3) == 1) acc1 += v;
        else if ((p & 3) == 2) acc2 += v;
        else                   acc3 += v;
    }
    return (acc0 + acc1) + (acc2 + acc3);
}

__global__ __launch_bounds__(256) void vfe_out(
    const float* __restrict__ x, const int* __restrict__ vnp,
    const float* __restrict__ W, const float* __restrict__ b,
    const float* __restrict__ gamma, const float* __restrict__ beta,
    const float* __restrict__ ws, float* __restrict__ out, int M)
{
    const int lane = threadIdx.x & 63;            // channel
    const int wid  = threadIdx.x >> 6;
    const int gw   = blockIdx.x * 4 + wid;        // global wave id

    // Sum the NSET accumulator sets (uniform float4 loads, once per wave)
    const float4* __restrict__ ws4 = (const float4*)ws;
    float4 m4[4];
    #pragma unroll
    for (int k = 0; k < 4; ++k) {
        float4 s = ws4[k];
        #pragma unroll
        for (int j = 1; j < NSET; ++j) {
            const float4 t = ws4[j * 4 + k];
            s.x += t.x; s.y += t.y; s.z += t.z; s.w += t.w;
        }
        m4[k] = s;
    }
    const float mom[NMOM] = { m4[0].x, m4[0].y, m4[0].z, m4[0].w,
                              m4[1].x, m4[1].y, m4[1].z, m4[1].w,
                              m4[2].x, m4[2].y, m4[2].z, m4[2].w,
                              m4[3].x, m4[3].y, m4[3].z };

    // Per-lane BN affine from the 15 moments
    const float4 w4  = ((const float4*)W)[lane];
    const float bias = b[lane];
    const float cnt  = mom[14];
    const float nv   = fmaxf(cnt, 1.0f);
    const float wdots = w4.x*mom[0] + w4.y*mom[1] + w4.z*mom[2] + w4.w*mom[3];
    const float mu   = (wdots + cnt * bias) / nv;
    const float q2 = mom[4]*w4.x*w4.x + mom[8]*w4.y*w4.y + mom[11]*w4.z*w4.z + mom[13]*w4.w*w4.w
                   + 2.f*(mom[5]*w4.x*w4.y + mom[6]*w4.x*w4.z + mom[7]*w4.x*w4.w
                        + mom[9]*w4.y*w4.z + mom[10]*w4.y*w4.w + mom[12]*w4.z*w4.w);
    const float SS  = q2 + 2.f*bias*wdots + cnt*bias*bias;   // sum h^2 over valid
    const float var = fmaxf(SS / nv - mu * mu, 0.f);
    const float A   = gamma[lane] * rsqrtf(var + EPS);
    const float B   = fmaf(-mu, A, beta[lane]);
    // fold: relu(h*A+B) = relu(dot(q, w*A) + (b*A+B))
    const float4 wA = make_float4(w4.x * A, w4.y * A, w4.z * A, w4.w * A);
    const float  c0 = fmaf(bias, A, B);

    const int m_base = gw * 4;
    if (m_base >= M) return;

    int4 n4;
    if (m_base + 3 < M) {
        n4 = *(const int4*)(vnp + m_base);        // one 16B wave-uniform load
    } else {
        n4.x = vnp[m_base];
        n4.y = (m_base + 1 < M) ? vnp[m_base + 1] : 0;
        n4.z = (m_base + 2 < M) ? vnp[m_base + 2] : 0;
        n4.w = (m_base + 3 < M) ? vnp[m_base + 3] : 0;
    }
    const int ns[4] = { n4.x, n4.y, n4.z, n4.w };

    #pragma unroll
    for (int v = 0; v < 4; ++v) {
        const int m = m_base + v;
        if (m >= M) break;                        // uniform branch
        const int n = ns[v];
        const float4* __restrict__ xq = (const float4*)x + (size_t)m * MAX_POINTS;
        float acc;
        if      (n > 24) acc = voxel_body<32>(xq, n, wA, c0);
        else if (n > 16) acc = voxel_body<24>(xq, n, wA, c0);
        else if (n >  8) acc = voxel_body<16>(xq, n, wA, c0);
        else if (n >  0) acc = voxel_body< 8>(xq, n, wA, c0);
        else             acc = 0.f;
        const float rn = 1.0f / fmaxf((float)n, 1.0f);
        out[(size_t)m * C_OUT + lane] = acc * rn; // coalesced 256 B/wave store
    }
}

extern "C" void kernel_launch(void* const* d_in, const int* in_sizes, int n_in,
                              void* d_out, int out_size, void* d_ws, size_t ws_size,
                              hipStream_t stream) {
    const float* x     = (const float*)d_in[0];
    const int*   vnp   = (const int*)  d_in[1];
    const float* W     = (const float*)d_in[2];
    const float* b     = (const float*)d_in[3];
    const float* gamma = (const float*)d_in[4];
    const float* beta  = (const float*)d_in[5];
    float* out = (float*)d_out;
    float* ws  = (float*)d_ws;
    const int M = in_sizes[1];                    // 40000 voxels

    hipMemsetAsync(d_ws, 0, WS_FLOATS * sizeof(float), stream);
    vfe_stats<<<STATS_BLOCKS, 256, 0, stream>>>(x, vnp, ws, M);
    const int nwaves = (M + 3) / 4;               // 4 voxels per wave
    const int nblk   = (nwaves + 3) / 4;          // 4 waves per block
    vfe_out<<<nblk, 256, 0, stream>>>(x, vnp, W, b, gamma, beta, ws, out, M);
}

// Round 7
// 113.401 us; speedup vs baseline: 1.4618x; 1.0187x over previous
//
#include <hip/hip_runtime.h>

#define MAX_POINTS 32
#define C_OUT 64
#define EPS 1e-5f

// ws layout (floats): NSET accumulator sets, 16 floats each (64 B apart).
// set s, moment i -> ws[s*16 + i]
//  i in [0..3]  : sum x   (sx, sy, sz, sw)
//  i in [4..13] : second moments xx,xy,xz,xw,yy,yz,yw,zz,zw,ww
//  i == 14      : valid-point count
// No fence / no finalize (R5: per-block device fence cost ~60 us).
#define NMOM 15
#define NSET 16
#define WS_FLOATS (NSET * 16)
#define STATS_BLOCKS 1024

// ---------------- Pass 1: 15-scalar moment reduction (streaming) ------------
__global__ __launch_bounds__(256) void vfe_stats(
    const float* __restrict__ x, const int* __restrict__ vnp,
    float* __restrict__ ws, int M)
{
    const int tid    = blockIdx.x * 256 + threadIdx.x;
    const int stride = gridDim.x * 256;
    const int total  = M * MAX_POINTS;            // flat float4 slots

    float a[NMOM];
    #pragma unroll
    for (int i = 0; i < NMOM; ++i) a[i] = 0.f;

    const float4* __restrict__ xq = (const float4*)x;

    // 2x-unrolled grid-stride: two independent load pairs in flight per iter
    int i = tid;
    for (; i + stride < total; i += 2 * stride) {
        const int i2 = i + stride;
        const float4 q0 = xq[i];                  // all four loads issue
        const float4 q1 = xq[i2];                 // before any use
        const int    n0 = vnp[i  >> 5];
        const int    n1 = vnp[i2 >> 5];
        const float mk0 = ((i  & 31) < n0) ? 1.f : 0.f;
        const float mk1 = ((i2 & 31) < n1) ? 1.f : 0.f;
        const float ax = q0.x*mk0, ay = q0.y*mk0, az = q0.z*mk0, aw = q0.w*mk0;
        const float bx = q1.x*mk1, by = q1.y*mk1, bz = q1.z*mk1, bw = q1.w*mk1;
        a[0] += ax + bx; a[1] += ay + by; a[2] += az + bz; a[3] += aw + bw;
        a[4]  = fmaf(ax, ax, fmaf(bx, bx, a[4]));
        a[5]  = fmaf(ax, ay, fmaf(bx, by, a[5]));
        a[6]  = fmaf(ax, az, fmaf(bx, bz, a[6]));
        a[7]  = fmaf(ax, aw, fmaf(bx, bw, a[7]));
        a[8]  = fmaf(ay, ay, fmaf(by, by, a[8]));
        a[9]  = fmaf(ay, az, fmaf(by, bz, a[9]));
        a[10] = fmaf(ay, aw, fmaf(by, bw, a[10]));
        a[11] = fmaf(az, az, fmaf(bz, bz, a[11]));
        a[12] = fmaf(az, aw, fmaf(bz, bw, a[12]));
        a[13] = fmaf(aw, aw, fmaf(bw, bw, a[13]));
        a[14] += mk0 + mk1;
    }
    for (; i < total; i += stride) {
        const float4 q0 = xq[i];
        const int    n  = vnp[i >> 5];
        const float  mk = ((i & 31) < n) ? 1.f : 0.f;
        const float qx = q0.x*mk, qy = q0.y*mk, qz = q0.z*mk, qw = q0.w*mk;
        a[0] += qx; a[1] += qy; a[2] += qz; a[3] += qw;
        a[4]  = fmaf(qx, qx, a[4]);
        a[5]  = fmaf(qx, qy, a[5]);
        a[6]  = fmaf(qx, qz, a[6]);
        a[7]  = fmaf(qx, qw, a[7]);
        a[8]  = fmaf(qy, qy, a[8]);
        a[9]  = fmaf(qy, qz, a[9]);
        a[10] = fmaf(qy, qw, a[10]);
        a[11] = fmaf(qz, qz, a[11]);
        a[12] = fmaf(qz, qw, a[12]);
        a[13] = fmaf(qw, qw, a[13]);
        a[14] += mk;
    }

    // wave reduce (64 lanes)
    #pragma unroll
    for (int k = 0; k < NMOM; ++k) {
        float v = a[k];
        #pragma unroll
        for (int off = 32; off > 0; off >>= 1)
            v += __shfl_down(v, off, 64);
        a[k] = v;
    }

    // block reduce: 4 waves -> LDS -> 15 atomics into this block's set
    __shared__ float bl[4][NMOM];
    const int lane = threadIdx.x & 63;
    const int wid  = threadIdx.x >> 6;
    if (lane == 0) {
        #pragma unroll
        for (int k = 0; k < NMOM; ++k) bl[wid][k] = a[k];
    }
    __syncthreads();
    if (threadIdx.x < NMOM) {
        const int k = threadIdx.x;
        const int set = blockIdx.x & (NSET - 1);  // spread over 16 L2 lines
        atomicAdd(&ws[set * 16 + k], bl[0][k] + bl[1][k] + bl[2][k] + bl[3][k]);
    }
}

// ---------------- Pass 2: fixed-unroll branchless bodies --------------------
// Wave = 8 voxels, lane = channel. BN affine folded: v = relu(dot(q,wA)+c0).
// Fixed trip count NP -> all broadcast loads issue back-to-back.
template<int NP>
__device__ __forceinline__ float voxel_body(
    const float4* __restrict__ xq, int n, float4 wA, float c0)
{
    float acc0 = 0.f, acc1 = 0.f, acc2 = 0.f, acc3 = 0.f;
    #pragma unroll
    for (int p = 0; p < NP; ++p) {
        const float4 q = xq[p];
        float v = fmaf(q.x, wA.x, fmaf(q.y, wA.y,
                  fmaf(q.z, wA.z, fmaf(q.w, wA.w, c0))));
        v = fmaxf(v, 0.f);
        if (p >= NP - 8) v = (p < n) ? v : 0.f;   // only last 8 need the mask
        if      ((p & 3) == 0) acc0 += v;
        else if ((p & 3) == 1) acc1 += v;
        else if ((p & 3) == 2) acc2 += v;
        else                   acc3 += v;
    }
    return (acc0 + acc1) + (acc2 + acc3);
}

__global__ __launch_bounds__(256) void vfe_out(
    const float* __restrict__ x, const int* __restrict__ vnp,
    const float* __restrict__ W, const float* __restrict__ b,
    const float* __restrict__ gamma, const float* __restrict__ beta,
    const float* __restrict__ ws, float* __restrict__ out, int M)
{
    const int lane = threadIdx.x & 63;            // channel
    const int wid  = threadIdx.x >> 6;

    // Block-level moment sum: wave 0 computes, everyone reads (amortize 4x).
    __shared__ float smom[NMOM];
    if (threadIdx.x < NSET) {
        // lane t sums moments of set t partially? simpler: lane t handles
        // moment t across all sets (t < NMOM).
    }
    if (threadIdx.x < NMOM) {
        const int k = threadIdx.x;
        float s = 0.f;
        #pragma unroll
        for (int j = 0; j < NSET; ++j) s += ws[j * 16 + k];
        smom[k] = s;
    }
    __syncthreads();
    float mom[NMOM];
    #pragma unroll
    for (int k = 0; k < NMOM; ++k) mom[k] = smom[k];

    // Per-lane BN affine from the 15 moments
    const float4 w4  = ((const float4*)W)[lane];
    const float bias = b[lane];
    const float cnt  = mom[14];
    const float nv   = fmaxf(cnt, 1.0f);
    const float wdots = w4.x*mom[0] + w4.y*mom[1] + w4.z*mom[2] + w4.w*mom[3];
    const float mu   = (wdots + cnt * bias) / nv;
    const float q2 = mom[4]*w4.x*w4.x + mom[8]*w4.y*w4.y + mom[11]*w4.z*w4.z + mom[13]*w4.w*w4.w
                   + 2.f*(mom[5]*w4.x*w4.y + mom[6]*w4.x*w4.z + mom[7]*w4.x*w4.w
                        + mom[9]*w4.y*w4.z + mom[10]*w4.y*w4.w + mom[12]*w4.z*w4.w);
    const float SS  = q2 + 2.f*bias*wdots + cnt*bias*bias;   // sum h^2 over valid
    const float var = fmaxf(SS / nv - mu * mu, 0.f);
    const float A   = gamma[lane] * rsqrtf(var + EPS);
    const float B   = fmaf(-mu, A, beta[lane]);
    // fold: relu(h*A+B) = relu(dot(q, w*A) + (b*A+B))
    const float4 wA = make_float4(w4.x * A, w4.y * A, w4.z * A, w4.w * A);
    const float  c0 = fmaf(bias, A, B);

    // 8 voxels per wave
    const int gw     = blockIdx.x * 4 + wid;      // global wave id
    const int m_base = gw * 8;
    if (m_base >= M) return;

    // counts for 8 voxels: two int4 uniform loads
    int ns[8];
    if (m_base + 7 < M) {
        const int4 na = *(const int4*)(vnp + m_base);
        const int4 nb = *(const int4*)(vnp + m_base + 4);
        ns[0]=na.x; ns[1]=na.y; ns[2]=na.z; ns[3]=na.w;
        ns[4]=nb.x; ns[5]=nb.y; ns[6]=nb.z; ns[7]=nb.w;
    } else {
        #pragma unroll
        for (int v = 0; v < 8; ++v)
            ns[v] = (m_base + v < M) ? vnp[m_base + v] : 0;
    }

    #pragma unroll
    for (int v = 0; v < 8; ++v) {
        const int m = m_base + v;
        if (m >= M) break;                        // uniform branch
        const int n = ns[v];
        const float4* __restrict__ xq = (const float4*)x + (size_t)m * MAX_POINTS;
        float acc;
        if      (n > 24) acc = voxel_body<32>(xq, n, wA, c0);
        else if (n > 16) acc = voxel_body<24>(xq, n, wA, c0);
        else if (n >  8) acc = voxel_body<16>(xq, n, wA, c0);
        else if (n >  0) acc = voxel_body< 8>(xq, n, wA, c0);
        else             acc = 0.f;
        const float rn = 1.0f / fmaxf((float)n, 1.0f);
        out[(size_t)m * C_OUT + lane] = acc * rn; // coalesced 256 B/wave store
    }
}

extern "C" void kernel_launch(void* const* d_in, const int* in_sizes, int n_in,
                              void* d_out, int out_size, void* d_ws, size_t ws_size,
                              hipStream_t stream) {
    const float* x     = (const float*)d_in[0];
    const int*   vnp   = (const int*)  d_in[1];
    const float* W     = (const float*)d_in[2];
    const float* b     = (const float*)d_in[3];
    const float* gamma = (const float*)d_in[4];
    const float* beta  = (const float*)d_in[5];
    float* out = (float*)d_out;
    float* ws  = (float*)d_ws;
    const int M = in_sizes[1];                    // 40000 voxels

    hipMemsetAsync(d_ws, 0, WS_FLOATS * sizeof(float), stream);
    vfe_stats<<<STATS_BLOCKS, 256, 0, stream>>>(x, vnp, ws, M);
    const int nwaves = (M + 7) / 8;               // 8 voxels per wave
    const int nblk   = (nwaves + 3) / 4;          // 4 waves per block
    vfe_out<<<nblk, 256, 0, stream>>>(x, vnp, W, b, gamma, beta, ws, out, M);
}